// Round 11
// baseline (120.069 us; speedup 1.0000x reference)
//
#include <hip/hip_runtime.h>

// N=512, D=512 pairwise scorer, all f32.
// left = E@W1[:D]; right = E@W1[D:]+b1; h = left[i]+right[j]; LN(D); GELU; @W2+b2; sigmoid.
// LN stats decompose over RAW (uncentered) rows:
//   var_h = var_l[i] + var_r[j] + 2*(dot_raw(i,j)/D - ml[i]*mr[j])
//   x_k   = ((l_k + r_k) - ml - mr) * rstd * g_k + be_k
// Two kernels. Never materialize [N,N,D].
// FIXED FLOOR: harness re-poison fill of d_ws (~42us @80% HBM) in timed stream.
// K_GEMM FROZEN (r4-r8 variants all null on total).
// VGPR-CAP MODEL: second __launch_bounds__ arg A => cap ~= 256/A; cap < live
// set => scratch spill (WRITE_SIZE tripwire). NEVER use a second arg here.
// r8 vs r10: packed math cut VALU-busy 25->19us but VGPR 52->108 cut
// occupancy 29->16.5% => net zero. k_pair is OCCUPANCY-bound. r11: scalar
// math (52 VGPR) + k-chunked LDS (16.6KB, 8 blocks/CU target).

#define N_ 512
#define D_ 512

// ---------------- K1: left/right GEMMs (FROZEN, r8 version) ----------------
__global__ __launch_bounds__(512) void k_gemm(const float* __restrict__ E,
                                              const float* __restrict__ W1,
                                              const float* __restrict__ b1,
                                              float* __restrict__ W /* [1024][512] */) {
    __shared__ float et[512 * 20];  // et[k][r]: addr k*20+r. 40KB. Overlaid by red[8][1024].

    const int t = threadIdx.x;
    const int bg = blockIdx.x;
    const int rg = bg >> 4;                 // 0..31 row group
    const int cg = bg & 15;                 // 0..15 col group (64 combined cols)
    const int r0 = rg * 16;
    const int half = cg >> 3;               // 0: left, 1: right(+b1)
    const int cb = (cg & 7) << 6;           // col base within half (0..448)

    for (int x = t; x < 16 * 128; x += 512) {
        const int r = x >> 7, k4 = (x & 127) << 2;
        float4 v = *(const float4*)&E[(r0 + r) * D_ + k4];
        et[(k4 + 0) * 20 + r] = v.x;
        et[(k4 + 1) * 20 + r] = v.y;
        et[(k4 + 2) * 20 + r] = v.z;
        et[(k4 + 3) * 20 + r] = v.w;
    }
    __syncthreads();

    const int lane = t & 63;
    const int ks = t >> 6;                  // 0..7
    const int kb = ks << 6;
    const int c4 = (lane & 15) << 2;        // 0..60
    const int rq = ((lane >> 4) & 3) << 2;  // 0,4,8,12
    const float* __restrict__ wp = W1 + (half << 18) + (kb << 9) + cb + c4;

    float4 a0 = {0.f, 0.f, 0.f, 0.f}, a1 = {0.f, 0.f, 0.f, 0.f};
    float4 a2 = {0.f, 0.f, 0.f, 0.f}, a3 = {0.f, 0.f, 0.f, 0.f};
#pragma unroll 16
    for (int k = 0; k < 64; ++k) {
        float4 wv = *(const float4*)(wp + (k << 9));
        float4 ev = *(const float4*)&et[(kb + k) * 20 + rq];
        a0.x = fmaf(ev.x, wv.x, a0.x); a0.y = fmaf(ev.x, wv.y, a0.y);
        a0.z = fmaf(ev.x, wv.z, a0.z); a0.w = fmaf(ev.x, wv.w, a0.w);
        a1.x = fmaf(ev.y, wv.x, a1.x); a1.y = fmaf(ev.y, wv.y, a1.y);
        a1.z = fmaf(ev.y, wv.z, a1.z); a1.w = fmaf(ev.y, wv.w, a1.w);
        a2.x = fmaf(ev.z, wv.x, a2.x); a2.y = fmaf(ev.z, wv.y, a2.y);
        a2.z = fmaf(ev.z, wv.z, a2.z); a2.w = fmaf(ev.z, wv.w, a2.w);
        a3.x = fmaf(ev.w, wv.x, a3.x); a3.y = fmaf(ev.w, wv.y, a3.y);
        a3.z = fmaf(ev.w, wv.z, a3.z); a3.w = fmaf(ev.w, wv.w, a3.w);
    }

    __syncthreads();                         // all et reads done
    float* red = et;                         // red[ks][1024], 32KB
    const int ob = (ks << 10) + c4;
    *(float4*)&red[ob + ((rq + 0) << 6)] = a0;
    *(float4*)&red[ob + ((rq + 1) << 6)] = a1;
    *(float4*)&red[ob + ((rq + 2) << 6)] = a2;
    *(float4*)&red[ob + ((rq + 3) << 6)] = a3;
    __syncthreads();

    float2 s = {0.f, 0.f};
#pragma unroll
    for (int k2 = 0; k2 < 8; ++k2) {
        float2 p = *(const float2*)&red[(k2 << 10) + (t << 1)];
        s.x += p.x; s.y += p.y;
    }
    const int ro = t >> 5, co = (t << 1) & 63;
    if (half) {
        float2 bb = *(const float2*)&b1[cb + co];
        s.x += bb.x; s.y += bb.y;
    }
    *(float2*)&W[((half << 9) + r0 + ro) * D_ + cb + co] = s;
}

// ---------------- K2: fused stats -> cov -> rstd -> gelu-dot -> sigmoid ----
// r5/r8 scalar math + k-CHUNKED LDS: stage 256-k half tiles (ls/rs[8][260] =
// 16.6KB -> 8 blocks/CU co-resident, double the 33KB full-tile version).
// Sweep A (2 chunks): stats partials + cov partials. Sweep B (re-stage 2
// chunks): gelu dot. 7 barriers, but cross-block overlap hides them.
// Per-thread cov/gelu accumulation order identical to r8 (same ks k-sets,
// ascending) -> same numerics.

// gelu_tanh(x) = x * sigmoid(1.5957691*(x + 0.044715 x^3))
// q = log2(exp(-2y)) = x*(A*x^2+B), B = -2*log2e*0.79788456, A = B*0.044715
// x = ((l+r) - mm)*rst*g + be = fmaf(fmaf(s, RST, T2N), g, be), T2N = -mm*rst
#define GELU1(L, R, G, BE, WC, RST, T2N, ACC)                                 \
    do {                                                                      \
        float s_ = (L) + (R);                                                 \
        float x_ = fmaf(fmaf(s_, (RST), (T2N)), (G), (BE));                   \
        float q_ = x_ * fmaf(-0.10294340f, x_ * x_, -2.30220935f);            \
        float e_ = __builtin_amdgcn_exp2f(q_);                                \
        float ge_ = x_ * __builtin_amdgcn_rcpf(1.f + e_);                     \
        ACC = fmaf(ge_, (WC), ACC);                                           \
    } while (0)

#define GELU4(LQ, RQ, RST, T2N, ACC)                                          \
    do {                                                                      \
        GELU1(LQ.x, RQ.x, g4.x, be4.x, w4.x, RST, T2N, ACC);                  \
        GELU1(LQ.y, RQ.y, g4.y, be4.y, w4.y, RST, T2N, ACC);                  \
        GELU1(LQ.z, RQ.z, g4.z, be4.z, w4.z, RST, T2N, ACC);                  \
        GELU1(LQ.w, RQ.w, g4.w, be4.w, w4.w, RST, T2N, ACC);                  \
    } while (0)

#define DOT4(LQ, RQ, ACC)                                                     \
    ACC += LQ.x * RQ.x + LQ.y * RQ.y + LQ.z * RQ.z + LQ.w * RQ.w

#define BFLY(V)                                                               \
    do {                                                                      \
        V += __shfl_xor(V, 1, 64);                                            \
        V += __shfl_xor(V, 2, 64);                                            \
        V += __shfl_xor(V, 4, 64);                                            \
        V += __shfl_xor(V, 8, 64);                                            \
    } while (0)

#define RED64(V)                                                              \
    do {                                                                      \
        V += __shfl_xor(V, 32, 64);                                           \
        V += __shfl_xor(V, 16, 64);                                           \
        V += __shfl_xor(V, 8, 64);                                            \
        V += __shfl_xor(V, 4, 64);                                            \
        V += __shfl_xor(V, 2, 64);                                            \
        V += __shfl_xor(V, 1, 64);                                            \
    } while (0)

// stage one 256-k chunk of both tiles (each thread: 2 iters x 2 float4 loads)
#define STAGE(KB)                                                             \
    do {                                                                      \
        for (int x = t; x < 8 * 64; x += 256) {                               \
            int r_ = x >> 6, c4_ = (x & 63) << 2;                             \
            *(float4*)&ls[r_][c4_] =                                          \
                *(const float4*)&W[(Ibase + r_) * D_ + (KB) + c4_];           \
            *(float4*)&rs[r_][c4_] =                                          \
                *(const float4*)&W[(Jbase + r_) * D_ + (KB) + c4_];           \
        }                                                                     \
    } while (0)

// stats partial for one of this wave's 4 rows (one float4 per lane = 256 f)
#define STAT1(RR, SM, SQ)                                                     \
    do {                                                                      \
        const int row_ = (w << 2) + (RR);                                     \
        const float* p_ = (row_ < 8) ? &ls[row_][0] : &rs[row_ - 8][0];       \
        float4 a_ = *(const float4*)&p_[lane << 2];                           \
        SM += (a_.x + a_.y) + (a_.z + a_.w);                                  \
        SQ += a_.x * a_.x + a_.y * a_.y + a_.z * a_.z + a_.w * a_.w;          \
    } while (0)

__global__ __launch_bounds__(256) void k_pair(const float* __restrict__ W,
                                              const float* __restrict__ gf,
                                              const float* __restrict__ bef,
                                              const float* __restrict__ wf,
                                              const float* __restrict__ b2f,
                                              float* __restrict__ out) {
    __shared__ float ls[8][260];    // 260 mod 32 = 4 -> reads spread banks
    __shared__ float rs[8][260];    // 16.6KB total -> 8 blocks/CU
    __shared__ float smean[16];     // rows 0-7: ls, 8-15: rs
    __shared__ float svar[16];

    // decode upper-triangle tile index b -> (I, J), I<=J, 64 tile-rows
    const int b = blockIdx.x;
    int I = (int)((129.0f - sqrtf(16641.0f - 8.0f * (float)b)) * 0.5f);
    if (I < 0) I = 0;
    if (I > 63) I = 63;
#define S_(i) (64 * (i) - ((i) * ((i)-1)) / 2)
    while (S_(I) > b) --I;
    while (S_(I + 1) <= b) ++I;
    const int J = I + (b - S_(I));
#undef S_

    const int t = threadIdx.x;
    const int ks = t & 15;          // k-slice: lane bits 0..3 -> shfl-reducible
    const int pt = t >> 4;          // 0..15 pair-threads
    const int i1 = pt & 7;          // l-row
    const int j4 = (pt >> 3) * 4;   // r-col quad base (0 or 4)
    const int lane = t & 63, w = t >> 6;
    const int Ibase = I * 8, Jbase = N_ + J * 8;

    // ---- sweep A: stats partials + cov partials over 2 chunks ----
    float cv0 = 0.f, cv1 = 0.f, cv2 = 0.f, cv3 = 0.f;
    float sm0 = 0.f, sm1 = 0.f, sm2 = 0.f, sm3 = 0.f;
    float sq0 = 0.f, sq1 = 0.f, sq2 = 0.f, sq3 = 0.f;
    for (int c = 0; c < 2; ++c) {
        const int kb = c << 8;
        STAGE(kb);
        __syncthreads();
        STAT1(0, sm0, sq0); STAT1(1, sm1, sq1);
        STAT1(2, sm2, sq2); STAT1(3, sm3, sq3);
#pragma unroll
        for (int it = 0; it < 4; ++it) {
            const int kq = (it * 16 + ks) * 4;
            float4 la = *(float4*)&ls[i1][kq];
            float4 ra = *(float4*)&rs[j4][kq];
            float4 rb = *(float4*)&rs[j4 + 1][kq];
            float4 rc = *(float4*)&rs[j4 + 2][kq];
            float4 rd = *(float4*)&rs[j4 + 3][kq];
            DOT4(la, ra, cv0); DOT4(la, rb, cv1);
            DOT4(la, rc, cv2); DOT4(la, rd, cv3);
        }
        __syncthreads();            // LDS free for next chunk / sweep B
    }

    // ---- finalize stats (full-wave reduce, lane0 writes) ----
    RED64(sm0); RED64(sq0); RED64(sm1); RED64(sq1);
    RED64(sm2); RED64(sq2); RED64(sm3); RED64(sq3);
    if (lane == 0) {
        float mu;
        mu = sm0 * (1.f / D_); smean[(w << 2) + 0] = mu; svar[(w << 2) + 0] = fmaf(-mu, mu, sq0 * (1.f / D_));
        mu = sm1 * (1.f / D_); smean[(w << 2) + 1] = mu; svar[(w << 2) + 1] = fmaf(-mu, mu, sq1 * (1.f / D_));
        mu = sm2 * (1.f / D_); smean[(w << 2) + 2] = mu; svar[(w << 2) + 2] = fmaf(-mu, mu, sq2 * (1.f / D_));
        mu = sm3 * (1.f / D_); smean[(w << 2) + 3] = mu; svar[(w << 2) + 3] = fmaf(-mu, mu, sq3 * (1.f / D_));
    }

    // cov butterfly while stats settle; stage B chunk 0; ONE barrier covers both
    BFLY(cv0); BFLY(cv1); BFLY(cv2); BFLY(cv3);
    STAGE(0);
    __syncthreads();

    // ---- rstd + mean-shift in-register ----
    // varh = var_l + var_r + cv*(2/D) - 2*ml*mr + eps ; t2n = -(ml+mr)*rst
    const float ml0 = smean[i1];
    const float vl0 = svar[i1];
    const float mr0 = smean[8 + j4],     mr1 = smean[8 + j4 + 1];
    const float mr2 = smean[8 + j4 + 2], mr3 = smean[8 + j4 + 3];
    const float vr0 = svar[8 + j4],     vr1 = svar[8 + j4 + 1];
    const float vr2 = svar[8 + j4 + 2], vr3 = svar[8 + j4 + 3];
    const float rst0 = rsqrtf(vl0 + vr0 + cv0 * (2.f / D_) - 2.f * ml0 * mr0 + 1e-5f);
    const float rst1 = rsqrtf(vl0 + vr1 + cv1 * (2.f / D_) - 2.f * ml0 * mr1 + 1e-5f);
    const float rst2 = rsqrtf(vl0 + vr2 + cv2 * (2.f / D_) - 2.f * ml0 * mr2 + 1e-5f);
    const float rst3 = rsqrtf(vl0 + vr3 + cv3 * (2.f / D_) - 2.f * ml0 * mr3 + 1e-5f);
    const float t2n0 = -(ml0 + mr0) * rst0;
    const float t2n1 = -(ml0 + mr1) * rst1;
    const float t2n2 = -(ml0 + mr2) * rst2;
    const float t2n3 = -(ml0 + mr3) * rst3;

    // ---- sweep B: gelu dot over 2 re-staged chunks ----
    float ac0 = 0.f, ac1 = 0.f, ac2 = 0.f, ac3 = 0.f;
#pragma unroll
    for (int it = 0; it < 4; ++it) {        // chunk 0 (already staged)
        const int kq = (it * 16 + ks) * 4;
        float4 g4 = *(const float4*)&gf[kq];
        float4 be4 = *(const float4*)&bef[kq];
        float4 w4 = *(const float4*)&wf[kq];
        float4 la = *(float4*)&ls[i1][kq];
        float4 ra = *(float4*)&rs[j4][kq];
        float4 rb = *(float4*)&rs[j4 + 1][kq];
        float4 rc = *(float4*)&rs[j4 + 2][kq];
        float4 rd = *(float4*)&rs[j4 + 3][kq];
        GELU4(la, ra, rst0, t2n0, ac0); GELU4(la, rb, rst1, t2n1, ac1);
        GELU4(la, rc, rst2, t2n2, ac2); GELU4(la, rd, rst3, t2n3, ac3);
    }
    __syncthreads();
    STAGE(256);
    __syncthreads();
#pragma unroll
    for (int it = 0; it < 4; ++it) {        // chunk 1
        const int kq = (it * 16 + ks) * 4;
        float4 g4 = *(const float4*)&gf[256 + kq];
        float4 be4 = *(const float4*)&bef[256 + kq];
        float4 w4 = *(const float4*)&wf[256 + kq];
        float4 la = *(float4*)&ls[i1][kq];
        float4 ra = *(float4*)&rs[j4][kq];
        float4 rb = *(float4*)&rs[j4 + 1][kq];
        float4 rc = *(float4*)&rs[j4 + 2][kq];
        float4 rd = *(float4*)&rs[j4 + 3][kq];
        GELU4(la, ra, rst0, t2n0, ac0); GELU4(la, rb, rst1, t2n1, ac1);
        GELU4(la, rc, rst2, t2n2, ac2); GELU4(la, rd, rst3, t2n3, ac3);
    }
    BFLY(ac0); BFLY(ac1); BFLY(ac2); BFLY(ac3);

    // ---- sigmoid + mirrored store (ks==0 lane of each pair-thread) ----
    if (ks == 0) {
        const float bb = b2f[0];
        const float z0 = __builtin_amdgcn_rcpf(
            1.f + __builtin_amdgcn_exp2f(-1.44269504f * (ac0 + bb)));
        const float z1 = __builtin_amdgcn_rcpf(
            1.f + __builtin_amdgcn_exp2f(-1.44269504f * (ac1 + bb)));
        const float z2 = __builtin_amdgcn_rcpf(
            1.f + __builtin_amdgcn_exp2f(-1.44269504f * (ac2 + bb)));
        const float z3 = __builtin_amdgcn_rcpf(
            1.f + __builtin_amdgcn_exp2f(-1.44269504f * (ac3 + bb)));
        const int gi = Ibase + i1;
        const int gj0 = (Jbase - N_) + j4;
        if (I < J) {
            float4 o0 = {z0, z1, z2, z3};
            *(float4*)&out[gi * N_ + gj0] = o0;
            out[gj0 * N_ + gi] = z0;
            out[(gj0 + 1) * N_ + gi] = z1;
            out[(gj0 + 2) * N_ + gi] = z2;
            out[(gj0 + 3) * N_ + gi] = z3;
        } else {  // diagonal tile: only pairs gi<=gj are valid
            if (gi <= gj0)     { out[gi * N_ + gj0] = z0;       out[gj0 * N_ + gi] = z0; }
            if (gi <= gj0 + 1) { out[gi * N_ + gj0 + 1] = z1;   out[(gj0 + 1) * N_ + gi] = z1; }
            if (gi <= gj0 + 2) { out[gi * N_ + gj0 + 2] = z2;   out[(gj0 + 2) * N_ + gi] = z2; }
            if (gi <= gj0 + 3) { out[gi * N_ + gj0 + 3] = z3;   out[(gj0 + 3) * N_ + gi] = z3; }
        }
    }
}

extern "C" void kernel_launch(void* const* d_in, const int* in_sizes, int n_in,
                              void* d_out, int out_size, void* d_ws, size_t ws_size,
                              hipStream_t stream) {
    const float* E     = (const float*)d_in[0];
    const float* W1    = (const float*)d_in[1];
    const float* b1    = (const float*)d_in[2];
    const float* gamma = (const float*)d_in[3];
    const float* beta  = (const float*)d_in[4];
    const float* w2    = (const float*)d_in[5];
    const float* b2    = (const float*)d_in[6];
    float* out = (float*)d_out;

    float* lcrc = (float*)d_ws;       // [1024][512]: rows 0..511 lc, 512..1023 rc(+b1)

    k_gemm<<<512, 512, 0, stream>>>(E, W1, b1, lcrc);
    k_pair<<<2080, 256, 0, stream>>>(lcrc, gamma, beta, w2, b2, out);
}

// Round 12
// 119.949 us; speedup vs baseline: 1.0010x; 1.0010x over previous
//
#include <hip/hip_runtime.h>

// N=512, D=512 pairwise scorer, all f32.
// left = E@W1[:D]; right = E@W1[D:]+b1; h = left[i]+right[j]; LN(D); GELU; @W2+b2; sigmoid.
// LN stats decompose over RAW (uncentered) rows:
//   var_h = var_l[i] + var_r[j] + 2*(dot_raw(i,j)/D - ml[i]*mr[j])
//   x_k   = ((l_k + r_k) - ml - mr) * rstd * g_k + be_k
// Two kernels. Never materialize [N,N,D].
// FIXED FLOOR: harness re-poison fill of d_ws (~42us @80% HBM) in timed stream.
// ACCOUNTING (r3 gaps=7us): r8 total 117.4 = 42.4 fill + 42.0 pair + ~26 GEMM
// + 7 gaps. k_gemm floor ~5 -> THE remaining target.
// k_gemm r12 diagnosis: 512 blocks = 2 blocks/CU x 8 waves = 16 waves/CU
// grid-shape ceiling; unroll/cap knobs null (r4-r8) because wave supply, not
// ILP, limits. Fix: 1024 blocks x 512thr, 16.5KB LDS, <=64 VGPR -> 32 waves/CU.
// VGPR-CAP MODEL: second __launch_bounds__ arg A => cap ~= 256*(threads/512)/A
// ... empirically (512,2)->128, (512,4)/(256,4)->64, (256,3)->84. Cap < live
// set => scratch spill (WRITE_SIZE tripwire). Safe here: live ~50 < 64.
// K_PAIR PLATEAU (r8 42.0 / r10 packed 43.9 / r11 chunked 44.7): three shapes
// converge 42-45 -> issue-bound plateau; r8 version is final (52 VGPR, clean).

#define N_ 512
#define D_ 512

// ---------------- K1: left/right GEMMs (r12: occupancy reshape) ----------------
// 1024 blocks = 64 rowgrps (8 rows) x 16 colgrps (64 combined cols). 512 thr
// = 8 waves = 8 k-slices of 64 k. lane = 16 col-quads x 4 row-pairs.
// Per k: 1 global dwordx4 (W1, L2) + 2 broadcast ds_read_b32 (rows 4 banks
// apart, conflict-free) + 8 FMA. Slice partials reduced via 16KB LDS overlay.
// Accumulation order (k asc within slice, slices asc) identical to r8.
__global__ __launch_bounds__(512, 4) void k_gemm(const float* __restrict__ E,
                                                 const float* __restrict__ W1,
                                                 const float* __restrict__ b1,
                                                 float* __restrict__ W /* [1024][512] */) {
    __shared__ float e[8][516];   // 16.5KB; overlaid by red[8][512] (16KB)

    const int t = threadIdx.x;
    const int bg = blockIdx.x;
    const int rg = bg >> 4;                 // 0..63 row group
    const int cg = bg & 15;                 // 0..15 col group (64 combined cols)
    const int r0 = rg * 8;
    const int half = cg >> 3;               // 0: left, 1: right(+b1)
    const int cb = (cg & 7) << 6;           // col base within half (0..448)

    // stage E[r0..r0+7][0..511] plain, coalesced (2 float4 per thread)
    for (int x = t; x < 8 * 128; x += 512) {
        const int r = x >> 7, c4 = (x & 127) << 2;
        *(float4*)&e[r][c4] = *(const float4*)&E[(r0 + r) * D_ + c4];
    }
    __syncthreads();

    const int lane = t & 63;
    const int ks = t >> 6;                  // 0..7 k-slice
    const int kb = ks << 6;
    const int c4 = (lane & 15) << 2;        // 0..60
    const int r2 = ((lane >> 4) & 3) << 1;  // 0,2,4,6 row-pair base
    const float* __restrict__ wp = W1 + (half << 18) + (kb << 9) + cb + c4;

    float4 a0 = {0.f, 0.f, 0.f, 0.f}, a1 = {0.f, 0.f, 0.f, 0.f};
#pragma unroll 4
    for (int k = 0; k < 64; ++k) {
        float4 wv = *(const float4*)(wp + (k << 9));
        float e0 = e[r2][kb + k];
        float e1 = e[r2 + 1][kb + k];
        a0.x = fmaf(e0, wv.x, a0.x); a0.y = fmaf(e0, wv.y, a0.y);
        a0.z = fmaf(e0, wv.z, a0.z); a0.w = fmaf(e0, wv.w, a0.w);
        a1.x = fmaf(e1, wv.x, a1.x); a1.y = fmaf(e1, wv.y, a1.y);
        a1.z = fmaf(e1, wv.z, a1.z); a1.w = fmaf(e1, wv.w, a1.w);
    }

    __syncthreads();                         // all e reads done
    float* red = &e[0][0];                   // red[ks][512], 16KB
    const int ob = (ks << 9) + c4;
    *(float4*)&red[ob + ((r2 + 0) << 6)] = a0;   // row*64 + col
    *(float4*)&red[ob + ((r2 + 1) << 6)] = a1;
    __syncthreads();

    // thread t -> output (row t>>6, col t&63); sum 8 slice partials
    float s = 0.f;
#pragma unroll
    for (int k2 = 0; k2 < 8; ++k2) s += red[(k2 << 9) + t];
    const int ro = t >> 6, co = t & 63;
    if (half) s += b1[cb + co];
    W[((half << 9) + r0 + ro) * D_ + cb + co] = s;
}

// ---------------- K2: fused stats -> cov -> rstd -> gelu-dot -> sigmoid ----
// FINAL (r8 measured-best, byte-exact): 8x8 pair tiles, 2080 blocks x 256
// thr, 33KB LDS, VGPR 52 (< the (256,4) 64-cap -> no spill), 42.0us.

// gelu_tanh(x) = x * sigmoid(1.5957691*(x + 0.044715 x^3))
// q = log2(exp(-2y)) = x*(A*x^2+B), B = -2*log2e*0.79788456, A = B*0.044715
// x = ((l+r) - mm)*rst*g + be = fmaf(fmaf(s, RST, T2N), g, be), T2N = -mm*rst
#define GELU1(L, R, G, BE, WC, RST, T2N, ACC)                                 \
    do {                                                                      \
        float s_ = (L) + (R);                                                 \
        float x_ = fmaf(fmaf(s_, (RST), (T2N)), (G), (BE));                   \
        float q_ = x_ * fmaf(-0.10294340f, x_ * x_, -2.30220935f);            \
        float e_ = __builtin_amdgcn_exp2f(q_);                                \
        float ge_ = x_ * __builtin_amdgcn_rcpf(1.f + e_);                     \
        ACC = fmaf(ge_, (WC), ACC);                                           \
    } while (0)

#define GELU4(LQ, RQ, RST, T2N, ACC)                                          \
    do {                                                                      \
        GELU1(LQ.x, RQ.x, g4.x, be4.x, w4.x, RST, T2N, ACC);                  \
        GELU1(LQ.y, RQ.y, g4.y, be4.y, w4.y, RST, T2N, ACC);                  \
        GELU1(LQ.z, RQ.z, g4.z, be4.z, w4.z, RST, T2N, ACC);                  \
        GELU1(LQ.w, RQ.w, g4.w, be4.w, w4.w, RST, T2N, ACC);                  \
    } while (0)

#define DOT4(LQ, RQ, ACC)                                                     \
    ACC += LQ.x * RQ.x + LQ.y * RQ.y + LQ.z * RQ.z + LQ.w * RQ.w

#define BFLY(V)                                                               \
    do {                                                                      \
        V += __shfl_xor(V, 1, 64);                                            \
        V += __shfl_xor(V, 2, 64);                                            \
        V += __shfl_xor(V, 4, 64);                                            \
        V += __shfl_xor(V, 8, 64);                                            \
    } while (0)

__global__ __launch_bounds__(256, 4) void k_pair(const float* __restrict__ W,
                                                 const float* __restrict__ gf,
                                                 const float* __restrict__ bef,
                                                 const float* __restrict__ wf,
                                                 const float* __restrict__ b2f,
                                                 float* __restrict__ out) {
    __shared__ float ls[8][516];    // 516 mod 32 = 4 -> reads spread banks
    __shared__ float rs[8][516];
    __shared__ float smean[16];     // rows 0-7: ls, 8-15: rs
    __shared__ float svar[16];

    // decode upper-triangle tile index b -> (I, J), I<=J, 64 tile-rows
    const int b = blockIdx.x;
    int I = (int)((129.0f - sqrtf(16641.0f - 8.0f * (float)b)) * 0.5f);
    if (I < 0) I = 0;
    if (I > 63) I = 63;
#define S_(i) (64 * (i) - ((i) * ((i)-1)) / 2)
    while (S_(I) > b) --I;
    while (S_(I + 1) <= b) ++I;
    const int J = I + (b - S_(I));
#undef S_

    const int t = threadIdx.x;
    const int ks = t & 15;          // k-slice: lane bits 0..3 -> shfl-reducible
    const int pt = t >> 4;          // 0..15 pair-threads
    const int i1 = pt & 7;          // l-row
    const int j4 = (pt >> 3) * 4;   // r-col quad base (0 or 4)
    const int Ibase = I * 8, Jbase = N_ + J * 8;

    // ---- stage raw tiles (coalesced 1KB/row chunks, 4 iters) ----
    for (int x = t; x < 8 * 128; x += 256) {
        int r = x >> 7, c4 = (x & 127) << 2;
        *(float4*)&ls[r][c4] = *(const float4*)&W[(Ibase + r) * D_ + c4];
        *(float4*)&rs[r][c4] = *(const float4*)&W[(Jbase + r) * D_ + c4];
    }
    __syncthreads();

    // ---- per-row mean/var from resident tiles (wave-parallel, 4 rows/wave) --
    {
        const int lane = t & 63, w = t >> 6;
#pragma unroll
        for (int rr = 0; rr < 4; ++rr) {
            const int row = w * 4 + rr;                 // 0..15
            const float* p = (row < 8) ? &ls[row][0] : &rs[row - 8][0];
            float4 a = *(const float4*)&p[lane << 2];
            float4 c = *(const float4*)&p[256 + (lane << 2)];
            float sm = (a.x + a.y) + (a.z + a.w) + (c.x + c.y) + (c.z + c.w);
            float sq = a.x * a.x + a.y * a.y + a.z * a.z + a.w * a.w +
                       c.x * c.x + c.y * c.y + c.z * c.z + c.w * c.w;
#pragma unroll
            for (int off = 32; off > 0; off >>= 1) {
                sm += __shfl_xor(sm, off, 64);
                sq += __shfl_xor(sq, off, 64);
            }
            if (lane == 0) {
                float mu = sm * (1.f / D_);
                smean[row] = mu;
                svar[row] = fmaf(-mu, mu, sq * (1.f / D_));
            }
        }
    }
    __syncthreads();

    // ---- pass A: raw cov-dot (1 l-row x 4 r-rows, named scalar chains) ----
    float cv0 = 0.f, cv1 = 0.f, cv2 = 0.f, cv3 = 0.f;
    for (int it = 0; it < 8; ++it) {
        const int kq = (it * 16 + ks) * 4;
        float4 la = *(float4*)&ls[i1][kq];
        float4 ra = *(float4*)&rs[j4][kq];
        float4 rb = *(float4*)&rs[j4 + 1][kq];
        float4 rc = *(float4*)&rs[j4 + 2][kq];
        float4 rd = *(float4*)&rs[j4 + 3][kq];
        DOT4(la, ra, cv0); DOT4(la, rb, cv1); DOT4(la, rc, cv2); DOT4(la, rd, cv3);
    }
    BFLY(cv0); BFLY(cv1); BFLY(cv2); BFLY(cv3);

    // ---- rstd + mean-shift in-register ----
    // varh = var_l + var_r + cv*(2/D) - 2*ml*mr + eps ; t2n = -(ml+mr)*rst
    const float ml0 = smean[i1];
    const float vl0 = svar[i1];
    const float mr0 = smean[8 + j4],     mr1 = smean[8 + j4 + 1];
    const float mr2 = smean[8 + j4 + 2], mr3 = smean[8 + j4 + 3];
    const float vr0 = svar[8 + j4],     vr1 = svar[8 + j4 + 1];
    const float vr2 = svar[8 + j4 + 2], vr3 = svar[8 + j4 + 3];
    const float rst0 = rsqrtf(vl0 + vr0 + cv0 * (2.f / D_) - 2.f * ml0 * mr0 + 1e-5f);
    const float rst1 = rsqrtf(vl0 + vr1 + cv1 * (2.f / D_) - 2.f * ml0 * mr1 + 1e-5f);
    const float rst2 = rsqrtf(vl0 + vr2 + cv2 * (2.f / D_) - 2.f * ml0 * mr2 + 1e-5f);
    const float rst3 = rsqrtf(vl0 + vr3 + cv3 * (2.f / D_) - 2.f * ml0 * mr3 + 1e-5f);
    const float t2n0 = -(ml0 + mr0) * rst0;
    const float t2n1 = -(ml0 + mr1) * rst1;
    const float t2n2 = -(ml0 + mr2) * rst2;
    const float t2n3 = -(ml0 + mr3) * rst3;

    // ---- pass B: gelu dot over the same resident tiles ----
    float ac0 = 0.f, ac1 = 0.f, ac2 = 0.f, ac3 = 0.f;
    for (int it = 0; it < 8; ++it) {
        const int kq = (it * 16 + ks) * 4;
        float4 g4 = *(const float4*)&gf[kq];
        float4 be4 = *(const float4*)&bef[kq];
        float4 w4 = *(const float4*)&wf[kq];
        float4 la = *(float4*)&ls[i1][kq];
        float4 ra = *(float4*)&rs[j4][kq];
        float4 rb = *(float4*)&rs[j4 + 1][kq];
        float4 rc = *(float4*)&rs[j4 + 2][kq];
        float4 rd = *(float4*)&rs[j4 + 3][kq];
        GELU4(la, ra, rst0, t2n0, ac0); GELU4(la, rb, rst1, t2n1, ac1);
        GELU4(la, rc, rst2, t2n2, ac2); GELU4(la, rd, rst3, t2n3, ac3);
    }
    BFLY(ac0); BFLY(ac1); BFLY(ac2); BFLY(ac3);

    // ---- sigmoid + mirrored store (ks==0 lane of each pair-thread) ----
    if (ks == 0) {
        const float bb = b2f[0];
        const float z0 = __builtin_amdgcn_rcpf(
            1.f + __builtin_amdgcn_exp2f(-1.44269504f * (ac0 + bb)));
        const float z1 = __builtin_amdgcn_rcpf(
            1.f + __builtin_amdgcn_exp2f(-1.44269504f * (ac1 + bb)));
        const float z2 = __builtin_amdgcn_rcpf(
            1.f + __builtin_amdgcn_exp2f(-1.44269504f * (ac2 + bb)));
        const float z3 = __builtin_amdgcn_rcpf(
            1.f + __builtin_amdgcn_exp2f(-1.44269504f * (ac3 + bb)));
        const int gi = Ibase + i1;
        const int gj0 = (Jbase - N_) + j4;
        if (I < J) {
            float4 o0 = {z0, z1, z2, z3};
            *(float4*)&out[gi * N_ + gj0] = o0;
            out[gj0 * N_ + gi] = z0;
            out[(gj0 + 1) * N_ + gi] = z1;
            out[(gj0 + 2) * N_ + gi] = z2;
            out[(gj0 + 3) * N_ + gi] = z3;
        } else {  // diagonal tile: only pairs gi<=gj are valid
            if (gi <= gj0)     { out[gi * N_ + gj0] = z0;       out[gj0 * N_ + gi] = z0; }
            if (gi <= gj0 + 1) { out[gi * N_ + gj0 + 1] = z1;   out[(gj0 + 1) * N_ + gi] = z1; }
            if (gi <= gj0 + 2) { out[gi * N_ + gj0 + 2] = z2;   out[(gj0 + 2) * N_ + gi] = z2; }
            if (gi <= gj0 + 3) { out[gi * N_ + gj0 + 3] = z3;   out[(gj0 + 3) * N_ + gi] = z3; }
        }
    }
}

extern "C" void kernel_launch(void* const* d_in, const int* in_sizes, int n_in,
                              void* d_out, int out_size, void* d_ws, size_t ws_size,
                              hipStream_t stream) {
    const float* E     = (const float*)d_in[0];
    const float* W1    = (const float*)d_in[1];
    const float* b1    = (const float*)d_in[2];
    const float* gamma = (const float*)d_in[3];
    const float* beta  = (const float*)d_in[4];
    const float* w2    = (const float*)d_in[5];
    const float* b2    = (const float*)d_in[6];
    float* out = (float*)d_out;

    float* lcrc = (float*)d_ws;       // [1024][512]: rows 0..511 lc, 512..1023 rc(+b1)

    k_gemm<<<1024, 512, 0, stream>>>(E, W1, b1, lcrc);
    k_pair<<<2080, 256, 0, stream>>>(lcrc, gamma, beta, w2, b2, out);
}

// Round 13
// 115.520 us; speedup vs baseline: 1.0394x; 1.0383x over previous
//
#include <hip/hip_runtime.h>

// N=512, D=512 pairwise scorer, all f32.
// left = E@W1[:D]; right = E@W1[D:]+b1; h = left[i]+right[j]; LN(D); GELU; @W2+b2; sigmoid.
// LN stats decompose over RAW (uncentered) rows:
//   var_h = var_l[i] + var_r[j] + 2*(dot_raw(i,j)/D - ml[i]*mr[j])
//   x_k   = ((l_k + r_k) - ml - mr) * rstd * g_k + be_k
// Two kernels. Never materialize [N,N,D].
//
// FINAL CONFIG = best measured total (r5: 115.6us). Budget: 42.4 harness fill
// (fixed, in timed stream) + 42.0 k_pair + ~24 k_gemm + ~7 gaps.
// k_pair plateau: 3 shapes (r8 scalar 42.0 / r10 packed 43.9 / r11 chunked
//   44.7) -> issue-bound; packed math cut VALU-busy 25->19us but VGPR
//   52->108 cut occupancy 29->16.5% => net zero. Scalar 52-VGPR wins.
// k_gemm plateau: 4 shapes (r4/r5 24.2 / r8 26 / r12 reshape 27) -> per-SIMD
//   issue+L2-latency floor; insensitive to unroll, VGPR cap, waves/CU 16->32.
// VGPR-CAP MODEL (empirical): 2nd __launch_bounds__ arg A => hard cap
//   ((512,2)->128, (256,3)->84, (512,4)/(256,4)->64). cap < live set =>
//   scratch spill, WRITE_SIZE blows up 40-140MB. Here: gemm live ~80 < 128,
//   pair live 52 < 64 -> both safe.

#define N_ 512
#define D_ 512

// ---------------- K1: left/right GEMMs (r4/r5 best-measured) ----------------
// Block = 16 rows x 64 combined cols, K split 8-ways in-block (wave = 64-k
// slice). 512 blocks x 8 waves = 16 waves/CU. E tile staged TRANSPOSED in LDS
// (et[k][r], stride 20). Per k: 1 global dwordx4 (W1) + 1 ds_read_b128 +
// 16 FMA. W1 read once per block. Partials reduced via LDS overlay on et.
__global__ __launch_bounds__(512, 2) void k_gemm(const float* __restrict__ E,
                                                 const float* __restrict__ W1,
                                                 const float* __restrict__ b1,
                                                 float* __restrict__ W /* [1024][512] */) {
    __shared__ float et[512 * 20];  // et[k][r]: addr k*20+r. 40KB. Overlaid by red[8][1024].

    const int t = threadIdx.x;
    const int bg = blockIdx.x;
    const int rg = bg >> 4;                 // 0..31 row group
    const int cg = bg & 15;                 // 0..15 col group (64 combined cols)
    const int r0 = rg * 16;
    const int half = cg >> 3;               // 0: left, 1: right(+b1)
    const int cb = (cg & 7) << 6;           // col base within half (0..448)

    // ---- stage E[r0..r0+15][0..511] transposed: et[k*20 + r] ----
    for (int x = t; x < 16 * 128; x += 512) {
        const int r = x >> 7, k4 = (x & 127) << 2;
        float4 v = *(const float4*)&E[(r0 + r) * D_ + k4];
        et[(k4 + 0) * 20 + r] = v.x;
        et[(k4 + 1) * 20 + r] = v.y;
        et[(k4 + 2) * 20 + r] = v.z;
        et[(k4 + 3) * 20 + r] = v.w;
    }
    __syncthreads();

    // ---- main: wave = k-slice (64 k), lane = 16 col-quads x 4 row-quads ----
    const int lane = t & 63;
    const int ks = t >> 6;                  // 0..7
    const int kb = ks << 6;
    const int c4 = (lane & 15) << 2;        // 0..60
    const int rq = ((lane >> 4) & 3) << 2;  // 0,4,8,12
    const float* __restrict__ wp = W1 + (half << 18) + (kb << 9) + cb + c4;

    float4 a0 = {0.f, 0.f, 0.f, 0.f}, a1 = {0.f, 0.f, 0.f, 0.f};
    float4 a2 = {0.f, 0.f, 0.f, 0.f}, a3 = {0.f, 0.f, 0.f, 0.f};
#pragma unroll 8
    for (int k = 0; k < 64; ++k) {
        float4 wv = *(const float4*)(wp + (k << 9));
        float4 ev = *(const float4*)&et[(kb + k) * 20 + rq];
        a0.x = fmaf(ev.x, wv.x, a0.x); a0.y = fmaf(ev.x, wv.y, a0.y);
        a0.z = fmaf(ev.x, wv.z, a0.z); a0.w = fmaf(ev.x, wv.w, a0.w);
        a1.x = fmaf(ev.y, wv.x, a1.x); a1.y = fmaf(ev.y, wv.y, a1.y);
        a1.z = fmaf(ev.y, wv.z, a1.z); a1.w = fmaf(ev.y, wv.w, a1.w);
        a2.x = fmaf(ev.z, wv.x, a2.x); a2.y = fmaf(ev.z, wv.y, a2.y);
        a2.z = fmaf(ev.z, wv.z, a2.z); a2.w = fmaf(ev.z, wv.w, a2.w);
        a3.x = fmaf(ev.w, wv.x, a3.x); a3.y = fmaf(ev.w, wv.y, a3.y);
        a3.z = fmaf(ev.w, wv.z, a3.z); a3.w = fmaf(ev.w, wv.w, a3.w);
    }

    // ---- reduce the 8 k-slice partials via LDS overlay on et ----
    __syncthreads();                         // all et reads done
    float* red = et;                         // red[ks][1024], 32KB
    const int ob = (ks << 10) + c4;
    *(float4*)&red[ob + ((rq + 0) << 6)] = a0;
    *(float4*)&red[ob + ((rq + 1) << 6)] = a1;
    *(float4*)&red[ob + ((rq + 2) << 6)] = a2;
    *(float4*)&red[ob + ((rq + 3) << 6)] = a3;
    __syncthreads();

    // thread t -> outputs 2t, 2t+1 (row t>>5, cols (2t)&63)
    float2 s = {0.f, 0.f};
#pragma unroll
    for (int k2 = 0; k2 < 8; ++k2) {
        float2 p = *(const float2*)&red[(k2 << 10) + (t << 1)];
        s.x += p.x; s.y += p.y;
    }
    const int ro = t >> 5, co = (t << 1) & 63;
    if (half) {
        float2 bb = *(const float2*)&b1[cb + co];
        s.x += bb.x; s.y += bb.y;
    }
    *(float2*)&W[((half << 9) + r0 + ro) * D_ + cb + co] = s;
}

// ---------------- K2: fused stats -> cov -> rstd -> gelu-dot -> sigmoid ----
// FINAL (r5/r8 measured-best): 8x8 pair tiles, 2080 blocks x 256 thr (16 pt
// x 16 ks), 33KB LDS, VGPR 52 -> 42.0us, VALUBusy 60%, occ 29%.

// gelu_tanh(x) = x * sigmoid(1.5957691*(x + 0.044715 x^3))
// q = log2(exp(-2y)) = x*(A*x^2+B), B = -2*log2e*0.79788456, A = B*0.044715
// x = ((l+r) - mm)*rst*g + be = fmaf(fmaf(s, RST, T2N), g, be), T2N = -mm*rst
#define GELU1(L, R, G, BE, WC, RST, T2N, ACC)                                 \
    do {                                                                      \
        float s_ = (L) + (R);                                                 \
        float x_ = fmaf(fmaf(s_, (RST), (T2N)), (G), (BE));                   \
        float q_ = x_ * fmaf(-0.10294340f, x_ * x_, -2.30220935f);            \
        float e_ = __builtin_amdgcn_exp2f(q_);                                \
        float ge_ = x_ * __builtin_amdgcn_rcpf(1.f + e_);                     \
        ACC = fmaf(ge_, (WC), ACC);                                           \
    } while (0)

#define GELU4(LQ, RQ, RST, T2N, ACC)                                          \
    do {                                                                      \
        GELU1(LQ.x, RQ.x, g4.x, be4.x, w4.x, RST, T2N, ACC);                  \
        GELU1(LQ.y, RQ.y, g4.y, be4.y, w4.y, RST, T2N, ACC);                  \
        GELU1(LQ.z, RQ.z, g4.z, be4.z, w4.z, RST, T2N, ACC);                  \
        GELU1(LQ.w, RQ.w, g4.w, be4.w, w4.w, RST, T2N, ACC);                  \
    } while (0)

#define DOT4(LQ, RQ, ACC)                                                     \
    ACC += LQ.x * RQ.x + LQ.y * RQ.y + LQ.z * RQ.z + LQ.w * RQ.w

#define BFLY(V)                                                               \
    do {                                                                      \
        V += __shfl_xor(V, 1, 64);                                            \
        V += __shfl_xor(V, 2, 64);                                            \
        V += __shfl_xor(V, 4, 64);                                            \
        V += __shfl_xor(V, 8, 64);                                            \
    } while (0)

__global__ __launch_bounds__(256, 4) void k_pair(const float* __restrict__ W,
                                                 const float* __restrict__ gf,
                                                 const float* __restrict__ bef,
                                                 const float* __restrict__ wf,
                                                 const float* __restrict__ b2f,
                                                 float* __restrict__ out) {
    __shared__ float ls[8][516];    // 516 mod 32 = 4 -> reads spread banks
    __shared__ float rs[8][516];
    __shared__ float smean[16];     // rows 0-7: ls, 8-15: rs
    __shared__ float svar[16];

    // decode upper-triangle tile index b -> (I, J), I<=J, 64 tile-rows
    const int b = blockIdx.x;
    int I = (int)((129.0f - sqrtf(16641.0f - 8.0f * (float)b)) * 0.5f);
    if (I < 0) I = 0;
    if (I > 63) I = 63;
#define S_(i) (64 * (i) - ((i) * ((i)-1)) / 2)
    while (S_(I) > b) --I;
    while (S_(I + 1) <= b) ++I;
    const int J = I + (b - S_(I));
#undef S_

    const int t = threadIdx.x;
    const int ks = t & 15;          // k-slice: lane bits 0..3 -> shfl-reducible
    const int pt = t >> 4;          // 0..15 pair-threads
    const int i1 = pt & 7;          // l-row
    const int j4 = (pt >> 3) * 4;   // r-col quad base (0 or 4)
    const int Ibase = I * 8, Jbase = N_ + J * 8;

    // ---- stage raw tiles (coalesced 1KB/row chunks, 4 iters) ----
    for (int x = t; x < 8 * 128; x += 256) {
        int r = x >> 7, c4 = (x & 127) << 2;
        *(float4*)&ls[r][c4] = *(const float4*)&W[(Ibase + r) * D_ + c4];
        *(float4*)&rs[r][c4] = *(const float4*)&W[(Jbase + r) * D_ + c4];
    }
    __syncthreads();

    // ---- per-row mean/var from resident tiles (wave-parallel, 4 rows/wave) --
    {
        const int lane = t & 63, w = t >> 6;
#pragma unroll
        for (int rr = 0; rr < 4; ++rr) {
            const int row = w * 4 + rr;                 // 0..15
            const float* p = (row < 8) ? &ls[row][0] : &rs[row - 8][0];
            float4 a = *(const float4*)&p[lane << 2];
            float4 c = *(const float4*)&p[256 + (lane << 2)];
            float sm = (a.x + a.y) + (a.z + a.w) + (c.x + c.y) + (c.z + c.w);
            float sq = a.x * a.x + a.y * a.y + a.z * a.z + a.w * a.w +
                       c.x * c.x + c.y * c.y + c.z * c.z + c.w * c.w;
#pragma unroll
            for (int off = 32; off > 0; off >>= 1) {
                sm += __shfl_xor(sm, off, 64);
                sq += __shfl_xor(sq, off, 64);
            }
            if (lane == 0) {
                float mu = sm * (1.f / D_);
                smean[row] = mu;
                svar[row] = fmaf(-mu, mu, sq * (1.f / D_));
            }
        }
    }
    __syncthreads();

    // ---- pass A: raw cov-dot (1 l-row x 4 r-rows, named scalar chains) ----
    float cv0 = 0.f, cv1 = 0.f, cv2 = 0.f, cv3 = 0.f;
    for (int it = 0; it < 8; ++it) {
        const int kq = (it * 16 + ks) * 4;
        float4 la = *(float4*)&ls[i1][kq];
        float4 ra = *(float4*)&rs[j4][kq];
        float4 rb = *(float4*)&rs[j4 + 1][kq];
        float4 rc = *(float4*)&rs[j4 + 2][kq];
        float4 rd = *(float4*)&rs[j4 + 3][kq];
        DOT4(la, ra, cv0); DOT4(la, rb, cv1); DOT4(la, rc, cv2); DOT4(la, rd, cv3);
    }
    BFLY(cv0); BFLY(cv1); BFLY(cv2); BFLY(cv3);

    // ---- rstd + mean-shift in-register ----
    // varh = var_l + var_r + cv*(2/D) - 2*ml*mr + eps ; t2n = -(ml+mr)*rst
    const float ml0 = smean[i1];
    const float vl0 = svar[i1];
    const float mr0 = smean[8 + j4],     mr1 = smean[8 + j4 + 1];
    const float mr2 = smean[8 + j4 + 2], mr3 = smean[8 + j4 + 3];
    const float vr0 = svar[8 + j4],     vr1 = svar[8 + j4 + 1];
    const float vr2 = svar[8 + j4 + 2], vr3 = svar[8 + j4 + 3];
    const float rst0 = rsqrtf(vl0 + vr0 + cv0 * (2.f / D_) - 2.f * ml0 * mr0 + 1e-5f);
    const float rst1 = rsqrtf(vl0 + vr1 + cv1 * (2.f / D_) - 2.f * ml0 * mr1 + 1e-5f);
    const float rst2 = rsqrtf(vl0 + vr2 + cv2 * (2.f / D_) - 2.f * ml0 * mr2 + 1e-5f);
    const float rst3 = rsqrtf(vl0 + vr3 + cv3 * (2.f / D_) - 2.f * ml0 * mr3 + 1e-5f);
    const float t2n0 = -(ml0 + mr0) * rst0;
    const float t2n1 = -(ml0 + mr1) * rst1;
    const float t2n2 = -(ml0 + mr2) * rst2;
    const float t2n3 = -(ml0 + mr3) * rst3;

    // ---- pass B: gelu dot over the same resident tiles ----
    float ac0 = 0.f, ac1 = 0.f, ac2 = 0.f, ac3 = 0.f;
    for (int it = 0; it < 8; ++it) {
        const int kq = (it * 16 + ks) * 4;
        float4 g4 = *(const float4*)&gf[kq];
        float4 be4 = *(const float4*)&bef[kq];
        float4 w4 = *(const float4*)&wf[kq];
        float4 la = *(float4*)&ls[i1][kq];
        float4 ra = *(float4*)&rs[j4][kq];
        float4 rb = *(float4*)&rs[j4 + 1][kq];
        float4 rc = *(float4*)&rs[j4 + 2][kq];
        float4 rd = *(float4*)&rs[j4 + 3][kq];
        GELU4(la, ra, rst0, t2n0, ac0); GELU4(la, rb, rst1, t2n1, ac1);
        GELU4(la, rc, rst2, t2n2, ac2); GELU4(la, rd, rst3, t2n3, ac3);
    }
    BFLY(ac0); BFLY(ac1); BFLY(ac2); BFLY(ac3);

    // ---- sigmoid + mirrored store (ks==0 lane of each pair-thread) ----
    if (ks == 0) {
        const float bb = b2f[0];
        const float z0 = __builtin_amdgcn_rcpf(
            1.f + __builtin_amdgcn_exp2f(-1.44269504f * (ac0 + bb)));
        const float z1 = __builtin_amdgcn_rcpf(
            1.f + __builtin_amdgcn_exp2f(-1.44269504f * (ac1 + bb)));
        const float z2 = __builtin_amdgcn_rcpf(
            1.f + __builtin_amdgcn_exp2f(-1.44269504f * (ac2 + bb)));
        const float z3 = __builtin_amdgcn_rcpf(
            1.f + __builtin_amdgcn_exp2f(-1.44269504f * (ac3 + bb)));
        const int gi = Ibase + i1;
        const int gj0 = (Jbase - N_) + j4;
        if (I < J) {
            float4 o0 = {z0, z1, z2, z3};
            *(float4*)&out[gi * N_ + gj0] = o0;
            out[gj0 * N_ + gi] = z0;
            out[(gj0 + 1) * N_ + gi] = z1;
            out[(gj0 + 2) * N_ + gi] = z2;
            out[(gj0 + 3) * N_ + gi] = z3;
        } else {  // diagonal tile: only pairs gi<=gj are valid
            if (gi <= gj0)     { out[gi * N_ + gj0] = z0;       out[gj0 * N_ + gi] = z0; }
            if (gi <= gj0 + 1) { out[gi * N_ + gj0 + 1] = z1;   out[(gj0 + 1) * N_ + gi] = z1; }
            if (gi <= gj0 + 2) { out[gi * N_ + gj0 + 2] = z2;   out[(gj0 + 2) * N_ + gi] = z2; }
            if (gi <= gj0 + 3) { out[gi * N_ + gj0 + 3] = z3;   out[(gj0 + 3) * N_ + gi] = z3; }
        }
    }
}

extern "C" void kernel_launch(void* const* d_in, const int* in_sizes, int n_in,
                              void* d_out, int out_size, void* d_ws, size_t ws_size,
                              hipStream_t stream) {
    const float* E     = (const float*)d_in[0];
    const float* W1    = (const float*)d_in[1];
    const float* b1    = (const float*)d_in[2];
    const float* gamma = (const float*)d_in[3];
    const float* beta  = (const float*)d_in[4];
    const float* w2    = (const float*)d_in[5];
    const float* b2    = (const float*)d_in[6];
    float* out = (float*)d_out;

    float* lcrc = (float*)d_ws;       // [1024][512]: rows 0..511 lc, 512..1023 rc(+b1)

    k_gemm<<<512, 512, 0, stream>>>(E, W1, b1, lcrc);
    k_pair<<<2080, 256, 0, stream>>>(lcrc, gamma, beta, w2, b2, out);
}